// Round 7
// baseline (1117.658 us; speedup 1.0000x reference)
//
#include <hip/hip_runtime.h>
#include <stdint.h>

typedef unsigned int u32;
typedef unsigned long long u64;
typedef unsigned short ushort_t;

#define NANCH 36864        // 4096*9
#define NPRE 6000
#define NPOST 300
#define CAP 6144
#define NKEEP 6000         // exact top-k truncation
#define MROWS 6016         // mask rows padded (94*64)
#define MW 192             // u32 words per mask row (6144 bits)
#define NEG_INF_F (-1e30f)

typedef __attribute__((ext_vector_type(8))) __bf16 bf8_t;
typedef __attribute__((ext_vector_type(8))) unsigned short us8_t;
typedef __attribute__((ext_vector_type(16))) float f32x16;

union pun8 { us8_t u; bf8_t b; };

// monotonic float->uint mapping (ascending)
__device__ __forceinline__ u32 fsort(float f) {
    u32 u = __float_as_uint(f);
    return (u & 0x80000000u) ? ~u : (u | 0x80000000u);
}

// RNE float -> bf16 bits, and exact bf16 bits -> float
__device__ __forceinline__ unsigned short f2bf(float f) {
    u32 u = __float_as_uint(f);
    u32 r = (u + 0x7FFFu + ((u >> 16) & 1u)) >> 16;
    return (unsigned short)r;
}
__device__ __forceinline__ float bf2f(unsigned short s) {
    return __uint_as_float(((u32)s) << 16);
}

__device__ __forceinline__ int ctz32(u32 x) {
    return __builtin_ctz(x ? x : 1u);
}

// async global->LDS, 16B per lane; LDS dest = uniform base + lane*16
__device__ __forceinline__ void gl_lds16(const void* g, void* l) {
    __builtin_amdgcn_global_load_lds(
        (const __attribute__((address_space(1))) unsigned int*)(g),
        (__attribute__((address_space(3))) unsigned int*)(l), 16, 0, 0);
}

// Xs split-plane stride in us8 units: 4 img * 32 kc * 64 h * 2 half * 64 w
#define XS_SPL ((size_t)4 * 32 * 64 * 2 * 64)

// ---------------- fused setup: wpack(128) | tw1(128) | anch(144) | init(1) | xsplit(128, XL only)
__global__ void setup_k(const float* __restrict__ w1, const float* __restrict__ sw,
                        const float* __restrict__ lw, const float* __restrict__ x,
                        ushort_t* __restrict__ Wp, ushort_t* __restrict__ Xs,
                        float* __restrict__ wt1, float* __restrict__ out_anchor,
                        u32* __restrict__ cnt) {
    __shared__ float xt[16][2][64];
    const int bid = blockIdx.x;
    const int tid = threadIdx.x;
    if (bid < 128) {
        // weight prepack: fp32 OIHW -> bf16x3 split, MFMA-A-fragment order
        int T = bid * 256 + tid;
        int lane31 = T & 31;
        int cot    = (T >> 5) & 15;
        int khalf  = (T >> 9) & 1;
        int kc     = T >> 10;
        int co  = cot * 32 + lane31;
        int ci0 = kc * 16 + khalf * 8;
        int lane = lane31 + khalf * 32;
        const float* wr = w1 + (size_t)co * 4608 + (size_t)ci0 * 9;
        us8_t* P = (us8_t*)Wp;
        const size_t sa_stride = (size_t)9 * 32 * 16 * 64;
#pragma unroll
        for (int t = 0; t < 9; ++t) {
            us8_t vh, vm, vl;
#pragma unroll
            for (int j = 0; j < 8; ++j) {
                float v = wr[j * 9 + t];
                unsigned short h = f2bf(v); float r1 = v - bf2f(h);
                unsigned short m = f2bf(r1); float r2 = r1 - bf2f(m);
                vh[j] = h; vm[j] = m; vl[j] = f2bf(r2);
            }
            size_t base = ((((size_t)t) * 32 + kc) * 16 + cot) * 64 + lane;
            P[base] = vh;
            P[base + sa_stride] = vm;
            P[base + 2 * sa_stride] = vl;
        }
    } else if (bid < 256) {
        int i = (bid - 128) * 256 + tid;
        int ci = i >> 6;
        int ch = i & 63;
        float v = 0.f;
        if (ch < 18) v = sw[ch * 512 + ci];
        else if (ch < 54) v = lw[(ch - 18) * 512 + ci];
        wt1[i] = v;
    } else if (bid < 400) {
        int i = (bid - 256) * 256 + tid;
        if (i < NANCH) {
            int p = i / 9, a = i - p * 9;
            int y = p / 64, xq = p - y * 64;
            int r = a / 3, s = a - r * 3;
            const float rat[3] = {0.5f, 1.f, 2.f};
            const float scl[3] = {8.f, 16.f, 32.f};
            float hh = 16.f * scl[s] * sqrtf(rat[r]);
            float wwv = 16.f * scl[s] * sqrtf(1.f / rat[r]);
            float ab0 = 8.f - 0.5f * hh, ab1 = 8.f - 0.5f * wwv;
            float ab2 = 8.f + 0.5f * hh, ab3 = 8.f + 0.5f * wwv;
            float sy = 16.f * (float)y, sx = 16.f * (float)xq;
            ((float4*)out_anchor)[i] = make_float4(sy + ab0, sx + ab1, sy + ab2, sx + ab3);
        }
    } else if (bid == 400) {
        if (tid < 8) cnt[tid] = 0u;
    } else {
        // xsplit: x fp32 -> bf16x3 planes, layout [split][img][kc][h][half][w][ci8]
        int pk = bid - 401;                 // 0..127
        int img = pk >> 5, kc = pk & 31;
        us8_t* XP = (us8_t*)Xs;
        for (int h2 = 0; h2 < 32; ++h2) {
#pragma unroll
            for (int i = 0; i < 8; ++i) {
                int idx = i * 256 + tid;            // [ci 16][hrow 2][w 64]
                int ci = idx >> 7, rem = idx & 127, hrow = rem >> 6, w = rem & 63;
                int h = h2 * 2 + hrow;
                xt[ci][hrow][w] = x[(((size_t)img * 512 + kc * 16 + ci) * 64 + h) * 64 + w];
            }
            __syncthreads();
            {
                int hrow = tid >> 7, st = tid & 127, half = st >> 6, w = st & 63;
                int h = h2 * 2 + hrow;
                us8_t vh, vm, vl;
#pragma unroll
                for (int j = 0; j < 8; ++j) {
                    float v = xt[half * 8 + j][hrow][w];
                    unsigned short hb = f2bf(v); float r1 = v - bf2f(hb);
                    unsigned short mb = f2bf(r1); float r2 = r1 - bf2f(mb);
                    vh[j] = hb; vm[j] = mb; vl[j] = f2bf(r2);
                }
                size_t ob = ((((size_t)img * 32 + kc) * 64 + h) * 2 + half) * 64 + w;
                XP[ob] = vh;
                XP[XS_SPL + ob] = vm;
                XP[2 * XS_SPL + ob] = vl;
            }
            __syncthreads();
        }
    }
}

// ---------------- conv1 v3: bf16x6 MFMA, staging via global_load_lds from pre-split Xs
// Grid 512 (256 thr). Block: 128 co (coq) x 128 px (2 rows). Wave 2x2 subtile.
// LDS xs us layout: [split 3][half 2][rr 4][col 66][ci8]; cols 0/65 & invalid rows stay zero.
__global__ __launch_bounds__(256, 2) void conv_mfma_k(const ushort_t* __restrict__ Xs,
                                                      const ushort_t* __restrict__ Wp,
                                                      const float* __restrict__ bias,
                                                      float* __restrict__ feat) {
    __shared__ __align__(16) unsigned short xs[12672];   // 25344 B

    const int bid = blockIdx.x;
    const int xcd = bid & 7;
    const int rest = bid >> 3;
    const int coq = xcd >> 1;
    const int g = (xcd & 1) * 64 + rest;
    const int fimg = g >> 5;
    const int hp = g & 31;
    const int h0 = hp * 2;

    const int tid = threadIdx.x;
    const int lane = tid & 63;
    const int wv = tid >> 6;
    const int r = wv & 1;
    const int coh = (wv >> 1);
    const int col31 = lane & 31;
    const int halfk = lane >> 5;

    // zero LDS once (pad cols + halo rows rely on this)
    {
        u32* p = (u32*)xs;
        for (int i = tid; i < 6336; i += 256) p[i] = 0u;
    }
    __syncthreads();

    f32x16 acc[4];
#pragma unroll
    for (int q = 0; q < 4; ++q)
#pragma unroll
        for (int i = 0; i < 16; ++i) acc[q][i] = 0.f;

    const us8_t* Pw = (const us8_t*)Wp;
    const size_t sa_stride = (size_t)9 * 32 * 16 * 64;
    static const int sal[6] = {0, 0, 1, 0, 1, 2};
    static const int sbl[6] = {0, 1, 0, 2, 1, 0};

    for (int kc = 0; kc < 32; ++kc) {
        // stage: 24 wave-level global_load_lds (6 per wave), 1 KB each
#pragma unroll
        for (int q = 0; q < 6; ++q) {
            int i = wv * 6 + q;                 // 0..23
            int split = i >> 3;
            int rem = i & 7;
            int rr = rem >> 1;
            int half = rem & 1;
            int gh = h0 + rr - 1;
            if ((unsigned)gh < 64u) {
                const char* src = (const char*)Xs +
                    (((((size_t)split * 4 + fimg) * 32 + kc) * 64 + gh) * 2 + half) * 1024 +
                    (size_t)lane * 16;
                void* dst = (void*)&xs[(((split * 2 + half) * 4 + rr) * 66 + 1) * 8];
                gl_lds16(src, dst);
            }
        }
        __syncthreads();

#pragma unroll
        for (int t = 0; t < 9; ++t) {
            const int kh = t / 3, kw = t - kh * 3;
            pun8 Bf[3][2];
#pragma unroll
            for (int sb = 0; sb < 3; ++sb)
#pragma unroll
                for (int ps = 0; ps < 2; ++ps)
                    Bf[sb][ps].u = *(const us8_t*)&xs[(((sb * 2 + halfk) * 4 + (r + kh)) * 66 +
                                                      (ps * 32 + col31 + kw)) * 8];
            pun8 Af[3][2];
            size_t abase = (((size_t)t * 32 + kc) * 16 + coq * 4 + coh * 2) * 64 + lane;
#pragma unroll
            for (int sa = 0; sa < 3; ++sa)
#pragma unroll
                for (int cs = 0; cs < 2; ++cs)
                    Af[sa][cs].u = Pw[sa * sa_stride + abase + (size_t)cs * 64];
#pragma unroll
            for (int pp = 0; pp < 6; ++pp) {
                const int sa = sal[pp], sb = sbl[pp];
#pragma unroll
                for (int cs = 0; cs < 2; ++cs)
#pragma unroll
                    for (int ps = 0; ps < 2; ++ps)
                        acc[cs * 2 + ps] = __builtin_amdgcn_mfma_f32_32x32x16_bf16(
                            Af[sa][cs].b, Bf[sb][ps].b, acc[cs * 2 + ps], 0, 0, 0);
            }
        }
        __syncthreads();
    }

#pragma unroll
    for (int cs = 0; cs < 2; ++cs)
#pragma unroll
        for (int ps = 0; ps < 2; ++ps)
#pragma unroll
            for (int i = 0; i < 16; ++i) {
                int m = (i & 3) + 8 * (i >> 2) + 4 * halfk;
                int co = coq * 128 + coh * 64 + cs * 32 + m;
                float v = acc[cs * 2 + ps][i] + bias[co];
                v = v > 0.f ? v : 0.f;
                feat[(((size_t)fimg * 512 + co) * 64 + (h0 + r)) * 64 + (ps * 32 + col31)] = v;
            }
}

// ---------------- conv1 v2 (fallback): in-kernel staging from fp32 x ----------------
__global__ __launch_bounds__(256, 2) void conv_fb_k(const float* __restrict__ x,
                                                    const ushort_t* __restrict__ Wp,
                                                    const float* __restrict__ bias,
                                                    float* __restrict__ feat,
                                                    int img_base) {
    __shared__ __align__(16) unsigned short xsb[3 * 6336];

    const int bid = blockIdx.x;
    const int xcd = bid & 7;
    const int rest = bid >> 3;
    const int rest_max = gridDim.x >> 3;
    const int coq = xcd >> 1;
    const int g = (xcd & 1) * rest_max + rest;
    const int fimg = g >> 5;
    const int hp = g & 31;
    const int n = img_base + fimg;
    const int h0 = hp * 2;

    const int tid = threadIdx.x;
    const int lane = tid & 63;
    const int wv = tid >> 6;
    const int r = wv & 1;
    const int coh = (wv >> 1);
    const int col31 = lane & 31;
    const int halfk = lane >> 5;

    f32x16 acc[4];
#pragma unroll
    for (int q = 0; q < 4; ++q)
#pragma unroll
        for (int i = 0; i < 16; ++i) acc[q][i] = 0.f;

    const us8_t* Pw = (const us8_t*)Wp;
    const size_t sa_stride = (size_t)9 * 32 * 16 * 64;
    static const int sal[6] = {0, 0, 1, 0, 1, 2};
    static const int sbl[6] = {0, 1, 0, 2, 1, 0};

    for (int kc = 0; kc < 32; ++kc) {
        for (int e = tid; e < 528; e += 256) {
            int half = e & 1;
            int rc = e >> 1;
            int rr = rc / 66;
            int cc = rc - rr * 66;
            int gr = h0 + rr - 1;
            int gc = cc - 1;
            bool inb = ((unsigned)gr < 64u) && ((unsigned)gc < 64u);
            int ci0 = kc * 16 + half * 8;
            const float* xp = x + ((((size_t)n * 512 + ci0) * 64 + gr) * 64 + gc);
            us8_t vh, vm, vl;
#pragma unroll
            for (int j = 0; j < 8; ++j) {
                float v = inb ? xp[(size_t)j * 4096] : 0.f;
                unsigned short h = f2bf(v); float r1 = v - bf2f(h);
                unsigned short m = f2bf(r1); float r2 = r1 - bf2f(m);
                vh[j] = h; vm[j] = m; vl[j] = f2bf(r2);
            }
            int off = (rr * 66 + cc) * 24 + half * 8;
            *(us8_t*)&xsb[off] = vh;
            *(us8_t*)&xsb[6336 + off] = vm;
            *(us8_t*)&xsb[12672 + off] = vl;
        }
        __syncthreads();

#pragma unroll
        for (int t = 0; t < 9; ++t) {
            const int kh = t / 3, kw = t - kh * 3;
            pun8 Bf[3][2];
            int boff0 = ((r + kh) * 66 + (col31 + kw)) * 24 + halfk * 8;
#pragma unroll
            for (int sb = 0; sb < 3; ++sb)
#pragma unroll
                for (int ps = 0; ps < 2; ++ps)
                    Bf[sb][ps].u = *(const us8_t*)&xsb[sb * 6336 + boff0 + ps * (32 * 24)];
            pun8 Af[3][2];
            size_t abase = (((size_t)t * 32 + kc) * 16 + coq * 4 + coh * 2) * 64 + lane;
#pragma unroll
            for (int sa = 0; sa < 3; ++sa)
#pragma unroll
                for (int cs = 0; cs < 2; ++cs)
                    Af[sa][cs].u = Pw[sa * sa_stride + abase + (size_t)cs * 64];
#pragma unroll
            for (int pp = 0; pp < 6; ++pp) {
                const int sa = sal[pp], sb = sbl[pp];
#pragma unroll
                for (int cs = 0; cs < 2; ++cs)
#pragma unroll
                    for (int ps = 0; ps < 2; ++ps)
                        acc[cs * 2 + ps] = __builtin_amdgcn_mfma_f32_32x32x16_bf16(
                            Af[sa][cs].b, Bf[sb][ps].b, acc[cs * 2 + ps], 0, 0, 0);
            }
        }
        __syncthreads();
    }

#pragma unroll
    for (int cs = 0; cs < 2; ++cs)
#pragma unroll
        for (int ps = 0; ps < 2; ++ps)
#pragma unroll
            for (int i = 0; i < 16; ++i) {
                int m = (i & 3) + 8 * (i >> 2) + 4 * halfk;
                int co = coq * 128 + coh * 64 + cs * 32 + m;
                float v = acc[cs * 2 + ps][i] + bias[co];
                v = v > 0.f ? v : 0.f;
                feat[(((size_t)fimg * 512 + co) * 64 + (h0 + r)) * 64 + (ps * 32 + col31)] = v;
            }
}

// ---------------- head: 1x1 convs + softmax-fg + loc2bbox + clip + valid ----------------
__global__ __launch_bounds__(64) void head_k(const float* __restrict__ feat,
                                             const float* __restrict__ wt1,
                                             const float* __restrict__ sb,
                                             const float* __restrict__ lb,
                                             const int* __restrict__ img_h,
                                             const int* __restrict__ img_w,
                                             float* __restrict__ out_loc,
                                             float* __restrict__ out_sc,
                                             float* __restrict__ boxes,
                                             float* __restrict__ scf,
                                             int img_base) {
    const int lane = threadIdx.x;
    const int row = blockIdx.x;
    const int fimg = blockIdx.y;
    const int n = img_base + fimg;

    float acc[56];
#pragma unroll
    for (int i = 0; i < 56; i++) acc[i] = 0.f;

    for (int ci = 0; ci < 512; ++ci) {
        float f = feat[(((size_t)fimg * 512 + ci) * 64 + row) * 64 + lane];
        const float4* wp = (const float4*)(wt1 + ci * 64);
#pragma unroll
        for (int q = 0; q < 14; q++) {
            float4 w4 = wp[q];
            acc[q * 4 + 0] = fmaf(f, w4.x, acc[q * 4 + 0]);
            acc[q * 4 + 1] = fmaf(f, w4.y, acc[q * 4 + 1]);
            acc[q * 4 + 2] = fmaf(f, w4.z, acc[q * 4 + 2]);
            acc[q * 4 + 3] = fmaf(f, w4.w, acc[q * 4 + 3]);
        }
    }

    float ihf = (float)img_h[0];
    float iwf = (float)img_w[0];
    int p = row * 64 + lane;
    size_t base = (size_t)n * NANCH + (size_t)p * 9;
    float sy = 16.f * (float)row;
    float sx = 16.f * (float)lane;
    const float rat[3] = {0.5f, 1.f, 2.f};
    const float scl[3] = {8.f, 16.f, 32.f};

#pragma unroll
    for (int a = 0; a < 9; a++) {
        int rr = a / 3, s = a % 3;
        float hh = 16.f * scl[s] * sqrtf(rat[rr]);
        float wwv = 16.f * scl[s] * sqrtf(1.f / rat[rr]);
        float ab0 = 8.f - 0.5f * hh, ab1 = 8.f - 0.5f * wwv;
        float ab2 = 8.f + 0.5f * hh, ab3 = 8.f + 0.5f * wwv;
        float a0 = sy + ab0, a1c = sx + ab1, a2 = sy + ab2, a3 = sx + ab3;

        float s0 = acc[a * 2 + 0] + sb[a * 2 + 0];
        float s1 = acc[a * 2 + 1] + sb[a * 2 + 1];
        ((float2*)out_sc)[base + a] = make_float2(s0, s1);
        float m = fmaxf(s0, s1);
        float e0 = expf(s0 - m), e1 = expf(s1 - m);
        float fg = e1 / (e0 + e1);

        float dy = acc[18 + a * 4 + 0] + lb[a * 4 + 0];
        float dx = acc[18 + a * 4 + 1] + lb[a * 4 + 1];
        float dh = acc[18 + a * 4 + 2] + lb[a * 4 + 2];
        float dw = acc[18 + a * 4 + 3] + lb[a * 4 + 3];
        ((float4*)out_loc)[base + a] = make_float4(dy, dx, dh, dw);

        float h_ = a2 - a0, w_ = a3 - a1c;
        float cy = a0 + 0.5f * h_, cx = a1c + 0.5f * w_;
        float ncy = dy * h_ + cy, ncx = dx * w_ + cx;
        float nh = expf(dh) * h_, nw = expf(dw) * w_;
        float y1 = ncy - 0.5f * nh, x1 = ncx - 0.5f * nw;
        float y2 = ncy + 0.5f * nh, x2 = ncx + 0.5f * nw;
        y1 = fminf(fmaxf(y1, 0.f), ihf);
        x1 = fminf(fmaxf(x1, 0.f), iwf);
        y2 = fminf(fmaxf(y2, 0.f), ihf);
        x2 = fminf(fmaxf(x2, 0.f), iwf);
        float hs = y2 - y1, wsz = x2 - x1;
        bool valid = (hs >= 16.f) && (wsz >= 16.f);
        ((float4*)boxes)[base + a] = make_float4(y1, x1, y2, x2);
        scf[base + a] = valid ? fg : NEG_INF_F;
    }
}

// ---------------- radix select: exact rank-6000 value per batch ----------------
__global__ __launch_bounds__(1024) void radix_k(const float* __restrict__ scf, u32* __restrict__ uT) {
    const int b = blockIdx.x;
    const int tid = threadIdx.x;
    const float* s = scf + (size_t)b * NANCH;
    __shared__ u32 hist[256];
    __shared__ u32 sel_prefix;
    __shared__ int sel_rank;
    if (tid == 0) { sel_prefix = 0u; sel_rank = NPRE; }
    __syncthreads();
    for (int p = 3; p >= 0; --p) {
        for (int i = tid; i < 256; i += 1024) hist[i] = 0u;
        __syncthreads();
        u32 prefix = sel_prefix;
        u32 highmask = (p == 3) ? 0u : (0xFFFFFFFFu << ((p + 1) * 8));
        for (int i = tid; i < NANCH; i += 1024) {
            u32 u = fsort(s[i]);
            if ((u & highmask) == prefix)
                atomicAdd(&hist[(u >> (p * 8)) & 255], 1u);
        }
        __syncthreads();
        if (tid == 0) {
            int r = sel_rank;
            u32 accum = 0;
            int bsel = 0;
            for (int bb = 255; bb >= 0; --bb) {
                accum += hist[bb];
                if ((int)accum >= r) {
                    bsel = bb;
                    sel_rank = r - (int)(accum - hist[bb]);
                    break;
                }
            }
            sel_prefix = prefix | ((u32)bsel << (p * 8));
        }
        __syncthreads();
    }
    if (tid == 0) uT[b] = sel_prefix;
}

// ---------------- compact ----------------
__global__ void compact_k(const float* __restrict__ scf, const u32* __restrict__ uT,
                          u32* __restrict__ cnt, u32* __restrict__ cidx) {
    int b = blockIdx.y;
    int i = blockIdx.x * 256 + threadIdx.x;
    float s = scf[(size_t)b * NANCH + i];
    u32 u = fsort(s);
    if (u >= uT[b] && s > -5e29f) {
        u32 p = atomicAdd(&cnt[b], 1u);
        if (p < CAP) cidx[(size_t)b * CAP + p] = (u32)i;
    }
}

// ---------------- sort: per-batch bitonic desc, truncate 6000, gather boxes ----------------
__global__ __launch_bounds__(1024) void sort_k(const float* __restrict__ scf,
                                               const float* __restrict__ boxes,
                                               u32* __restrict__ cnt,
                                               const u32* __restrict__ cidx,
                                               float4* __restrict__ sbox) {
    __shared__ u64 sk[8192];
    const int b = blockIdx.x;
    const int tid = threadIdx.x;
    int count = (int)cnt[b];
    if (count > CAP) count = CAP;

    for (int i = tid; i < 8192; i += 1024) {
        u64 key = 0ull;
        if (i < count) {
            u32 idx = cidx[(size_t)b * CAP + i];
            u32 u = fsort(scf[(size_t)b * NANCH + idx]);
            key = ((u64)u << 32) | (u64)(0xFFFFFFFFu - idx);
        }
        sk[i] = key;
    }

    for (int k = 2; k <= 8192; k <<= 1) {
        for (int j = k >> 1; j > 0; j >>= 1) {
            __syncthreads();
            for (int i = tid; i < 8192; i += 1024) {
                int p = i ^ j;
                if (p > i) {
                    bool up = (i & k) == 0;
                    u64 a = sk[i], c = sk[p];
                    bool sw = up ? (a < c) : (a > c);
                    if (sw) { sk[i] = c; sk[p] = a; }
                }
            }
        }
    }
    __syncthreads();

    int S = count < NKEEP ? count : NKEEP;
    if (tid == 0) cnt[4 + b] = (u32)S;
    const float4* Bx = (const float4*)boxes;
    for (int i = tid; i < S; i += 1024) {
        u32 idx = 0xFFFFFFFFu - (u32)(sk[i] & 0xFFFFFFFFull);
        sbox[(size_t)b * CAP + i] = Bx[(size_t)b * NANCH + idx];
    }
}

// ---------------- mask build ----------------
__global__ __launch_bounds__(256) void mask_k(const float4* __restrict__ sbox,
                                              const u32* __restrict__ cnt,
                                              u32* __restrict__ mask) {
    __shared__ float4 rb[64];
    __shared__ float ra[64];
    const int tile = blockIdx.x;
    const int b = blockIdx.y;
    const int tid = threadIdx.x;
    const int lane = tid & 63;
    const int wv = tid >> 6;
    const int r0 = tile * 64;

    if (tid < 64) {
        float4 v = sbox[(size_t)b * CAP + (r0 + tid)];
        rb[tid] = v;
        ra[tid] = (v.z - v.x) * (v.w - v.y);
    }
    __syncthreads();

    for (int chunk = (tile >> 2); chunk < 24; ++chunk) {
        int c = chunk * 256 + tid;
        float4 cb = sbox[(size_t)b * CAP + c];
        float a2 = (cb.z - cb.x) * (cb.w - cb.y);
        u64 mine = 0ull;
#pragma unroll 4
        for (int r = 0; r < 64; ++r) {
            float4 rr = rb[r];
            float ty = fmaxf(rr.x, cb.x);
            float tx = fmaxf(rr.y, cb.y);
            float by = fminf(rr.z, cb.z);
            float bx = fminf(rr.w, cb.w);
            float ih = fmaxf(by - ty, 0.f);
            float iw = fmaxf(bx - tx, 0.f);
            float inter = ih * iw;
            float iou = inter / fmaxf(ra[r] + a2 - inter, 1e-6f);
            u64 bal = __ballot(iou > 0.7f);
            if (lane == r) mine = bal;
        }
        int row = r0 + lane;
        u64* dst = (u64*)(mask + ((size_t)b * MROWS + row) * MW);
        dst[chunk * 4 + wv] = mine;
    }
}

// ---------------- scan: serial greedy (wave 0) + L2-warmer waves ----------------
__global__ __launch_bounds__(1024) void scan_k(const u32* __restrict__ mask,
                                               const float4* __restrict__ sbox,
                                               const u32* __restrict__ cnt,
                                               u32* __restrict__ sink,
                                               float4* __restrict__ out_rois) {
    const int b = blockIdx.x;
    const int tid = threadIdx.x;
    const int wv = tid >> 6;
    const int lane = tid & 63;
    const int S = (int)cnt[4 + b];

    __shared__ int keep[NPOST];
    __shared__ int posS;
    volatile int* vpos = &posS;
    if (tid == 0) *vpos = 0;
    __syncthreads();

    const u32* mbase = mask + (size_t)b * MROWS * MW;

    if (wv == 0) {
        u32 a0, a1, a2v;
        {
            int w;
            w = lane;       a0  = (w * 32 + 32 <= S) ? 0xFFFFFFFFu : ((w * 32 < S) ? ((1u << (S - w * 32)) - 1u) : 0u);
            w = 64 + lane;  a1  = (w * 32 + 32 <= S) ? 0xFFFFFFFFu : ((w * 32 < S) ? ((1u << (S - w * 32)) - 1u) : 0u);
            w = 128 + lane; a2v = (w * 32 + 32 <= S) ? 0xFFFFFFFFu : ((w * 32 < S) ? ((1u << (S - w * 32)) - 1u) : 0u);
        }

        int it = 0;
        while (it < NPOST) {
            int j;
            u64 b0 = __ballot(a0 != 0u);
            if (b0) {
                int L = __builtin_ctzll(b0);
                int cv = (lane << 5) + ctz32(a0);
                j = __shfl(cv, L);
            } else {
                u64 b1 = __ballot(a1 != 0u);
                if (b1) {
                    int L = __builtin_ctzll(b1);
                    int cv = ((64 + lane) << 5) + ctz32(a1);
                    j = __shfl(cv, L);
                } else {
                    u64 b2 = __ballot(a2v != 0u);
                    if (!b2) break;
                    int L = __builtin_ctzll(b2);
                    int cv = ((128 + lane) << 5) + ctz32(a2v);
                    j = __shfl(cv, L);
                }
            }
            if (lane == 0) { keep[it] = j; *vpos = j; }
            ++it;

            int wj = j >> 5;
            u32 bit = 1u << (j & 31);
            if (wj == lane) a0 &= ~bit;
            else if (wj == 64 + lane) a1 &= ~bit;
            else if (wj == 128 + lane) a2v &= ~bit;

            const u32* row = mbase + (size_t)j * MW;
            u32 m0 = row[lane];
            u32 m1 = row[64 + lane];
            u32 m2 = row[128 + lane];
            a0 &= ~m0; a1 &= ~m1; a2v &= ~m2;
        }

        if (lane == 0) *vpos = (1 << 28);

        int total = it;
        for (int i = lane; i < NPOST; i += 64) {
            float4 v = make_float4(0.f, 0.f, 0.f, 0.f);
            if (i < total) v = sbox[(size_t)b * CAP + keep[i]];
            out_rois[(size_t)b * NPOST + i] = v;
        }
    } else {
        u32 dummy = 0u;
        const int W = 2048;
        for (int r = wv - 1; r < MROWS; r += 15) {
            int sp = 0;
            while (*vpos + W <= r && sp < 65536) { __builtin_amdgcn_s_sleep(2); ++sp; }
            if (*vpos >= (1 << 27)) break;
            const u32* row = mbase + (size_t)r * MW;
            dummy += row[lane] + row[64 + lane] + row[128 + lane];
        }
        if (dummy == 0xDEADBEEFu) sink[b] = dummy;
    }
}

// ---------------- launch ----------------
extern "C" void kernel_launch(void* const* d_in, const int* in_sizes, int n_in,
                              void* d_out, int out_size, void* d_ws, size_t ws_size,
                              hipStream_t stream) {
    const float* x  = (const float*)d_in[0];
    const float* w1 = (const float*)d_in[1];
    const float* b1 = (const float*)d_in[2];
    const float* sw = (const float*)d_in[3];
    const float* sb = (const float*)d_in[4];
    const float* lw = (const float*)d_in[5];
    const float* lb = (const float*)d_in[6];
    const int* ih   = (const int*)d_in[7];
    const int* iw   = (const int*)d_in[8];
    float* out = (float*)d_out;

    char* ws = (char*)d_ws;
    // XL layout: Wp[0,14155776) Xs[14155776,64487424) feat[64487424,98041856) RB=98041856
    // BIG layout (R6): Wp[0,..) feat@14286848 (4 img), RB=47841280
    // SMALL: feat 2 img, RB=31064064
    const size_t NEED_XL  = 101614080;
    const size_t NEED_BIG = 51413504;
    const int mode = (ws_size >= NEED_XL) ? 2 : (ws_size >= NEED_BIG ? 1 : 0);

    ushort_t* Wp  = (ushort_t*)(ws);
    ushort_t* Xs  = (ushort_t*)(ws + 14155776);
    float* feat   = (float*)(ws + (mode == 2 ? 64487424 : 14286848));
    u32* mask     = (u32*)(ws);                       // overlays dead Wp/Xs after head
    const size_t RB = (mode == 2) ? 98041856 : (mode == 1 ? 47841280 : 31064064);
    float* wt1    = (float*)(ws + RB);
    float* boxes  = (float*)(ws + RB + 131072);
    float* scf    = (float*)(ws + RB + 2490368);
    u32* uT       = (u32*)(ws + RB + 3080192);
    u32* cnt      = (u32*)(ws + RB + 3080448);
    u32* cidx     = (u32*)(ws + RB + 3080704);
    float4* sbox  = (float4*)(ws + RB + 3179008);

    float* out_loc = out;
    float* out_sc  = out + 589824;
    float4* out_roi = (float4*)(out + 884736);
    float* out_anc = out + 889536;

    hipLaunchKernelGGL(setup_k, dim3(mode == 2 ? 529 : 401), dim3(256), 0, stream,
                       w1, sw, lw, x, Wp, Xs, wt1, out_anc, cnt);

    if (mode == 2) {
        hipLaunchKernelGGL(conv_mfma_k, dim3(512), dim3(256), 0, stream, (const ushort_t*)Xs, Wp, b1, feat);
        hipLaunchKernelGGL(head_k, dim3(64, 4), dim3(64), 0, stream, feat, wt1, sb, lb, ih, iw,
                           out_loc, out_sc, boxes, scf, 0);
    } else if (mode == 1) {
        hipLaunchKernelGGL(conv_fb_k, dim3(512), dim3(256), 0, stream, x, Wp, b1, feat, 0);
        hipLaunchKernelGGL(head_k, dim3(64, 4), dim3(64), 0, stream, feat, wt1, sb, lb, ih, iw,
                           out_loc, out_sc, boxes, scf, 0);
    } else {
        for (int pass = 0; pass < 2; ++pass) {
            hipLaunchKernelGGL(conv_fb_k, dim3(256), dim3(256), 0, stream, x, Wp, b1, feat, pass * 2);
            hipLaunchKernelGGL(head_k, dim3(64, 2), dim3(64), 0, stream, feat, wt1, sb, lb, ih, iw,
                               out_loc, out_sc, boxes, scf, pass * 2);
        }
    }

    hipLaunchKernelGGL(radix_k, dim3(4), dim3(1024), 0, stream, scf, uT);
    hipLaunchKernelGGL(compact_k, dim3(144, 4), dim3(256), 0, stream, scf, uT, cnt, cidx);
    hipLaunchKernelGGL(sort_k, dim3(4), dim3(1024), 0, stream, scf, boxes, cnt, cidx, sbox);
    hipLaunchKernelGGL(mask_k, dim3(94, 4), dim3(256), 0, stream, sbox, cnt, mask);
    hipLaunchKernelGGL(scan_k, dim3(4), dim3(1024), 0, stream, mask, sbox, cnt, cidx, out_roi);
}

// Round 9
// 1021.534 us; speedup vs baseline: 1.0941x; 1.0941x over previous
//
#include <hip/hip_runtime.h>
#include <stdint.h>

typedef unsigned int u32;
typedef unsigned long long u64;
typedef unsigned short ushort_t;

#define NANCH 36864        // 4096*9
#define NPRE 6000
#define NPOST 300
#define CAP 6144           // sbox stride
#define NKEEP 6000
#define MROWS 6016
#define MW 192             // u32 words per mask row
#define NEG_INF_F (-1e30f)

typedef __attribute__((ext_vector_type(8))) __bf16 bf8_t;
typedef __attribute__((ext_vector_type(8))) unsigned short us8_t;
typedef __attribute__((ext_vector_type(16))) float f32x16;

union pun8 { us8_t u; bf8_t b; };

__device__ __forceinline__ u32 fsort(float f) {
    u32 u = __float_as_uint(f);
    return (u & 0x80000000u) ? ~u : (u | 0x80000000u);
}
__device__ __forceinline__ unsigned short f2bf(float f) {
    u32 u = __float_as_uint(f);
    u32 r = (u + 0x7FFFu + ((u >> 16) & 1u)) >> 16;
    return (unsigned short)r;
}
__device__ __forceinline__ float bf2f(unsigned short s) {
    return __uint_as_float(((u32)s) << 16);
}
__device__ __forceinline__ int ctz32(u32 x) {
    return __builtin_ctz(x ? x : 1u);
}
__device__ __forceinline__ void gl_lds16(const void* g, void* l) {
    __builtin_amdgcn_global_load_lds(
        (const __attribute__((address_space(1))) unsigned int*)(g),
        (__attribute__((address_space(3))) unsigned int*)(l), 16, 0, 0);
}

// Xs split-plane stride in us8 (16B) units: 4img*32kc*64h*2half*64w
#define XS_SPL ((size_t)4 * 32 * 64 * 2 * 64)
// Wp split stride in us8 units
#define WP_SPL ((size_t)9 * 32 * 16 * 64)

// ---------------- fused setup: wpack(128) | tw1(128) | anch(144) | xsplit(128, XL) ----------------
// bf16x3 splits (h,m,l) — 6-tier precision floor; bf16x3-tier failed NMS ties (R8).
__global__ void setup_k(const float* __restrict__ w1, const float* __restrict__ sw,
                        const float* __restrict__ lw, const float* __restrict__ x,
                        ushort_t* __restrict__ Wp, ushort_t* __restrict__ Xs,
                        float* __restrict__ wt1, float* __restrict__ out_anchor) {
    __shared__ float xt[16][2][64];
    const int bid = blockIdx.x;
    const int tid = threadIdx.x;
    if (bid < 128) {
        int T = bid * 256 + tid;
        int lane31 = T & 31;
        int cot    = (T >> 5) & 15;
        int khalf  = (T >> 9) & 1;
        int kc     = T >> 10;
        int co  = cot * 32 + lane31;
        int ci0 = kc * 16 + khalf * 8;
        int lane = lane31 + khalf * 32;
        const float* wr = w1 + (size_t)co * 4608 + (size_t)ci0 * 9;
        us8_t* P = (us8_t*)Wp;
#pragma unroll
        for (int t = 0; t < 9; ++t) {
            us8_t vh, vm, vl;
#pragma unroll
            for (int j = 0; j < 8; ++j) {
                float v = wr[j * 9 + t];
                unsigned short h = f2bf(v); float r1 = v - bf2f(h);
                unsigned short m = f2bf(r1); float r2 = r1 - bf2f(m);
                vh[j] = h; vm[j] = m; vl[j] = f2bf(r2);
            }
            size_t base = ((((size_t)t) * 32 + kc) * 16 + cot) * 64 + lane;
            P[base] = vh;
            P[base + WP_SPL] = vm;
            P[base + 2 * WP_SPL] = vl;
        }
    } else if (bid < 256) {
        int i = (bid - 128) * 256 + tid;
        int ci = i >> 6;
        int ch = i & 63;
        float v = 0.f;
        if (ch < 18) v = sw[ch * 512 + ci];
        else if (ch < 54) v = lw[(ch - 18) * 512 + ci];
        wt1[i] = v;
    } else if (bid < 400) {
        int i = (bid - 256) * 256 + tid;
        if (i < NANCH) {
            int p = i / 9, a = i - p * 9;
            int y = p / 64, xq = p - y * 64;
            int r = a / 3, s = a - r * 3;
            const float rat[3] = {0.5f, 1.f, 2.f};
            const float scl[3] = {8.f, 16.f, 32.f};
            float hh = 16.f * scl[s] * sqrtf(rat[r]);
            float wwv = 16.f * scl[s] * sqrtf(1.f / rat[r]);
            float ab0 = 8.f - 0.5f * hh, ab1 = 8.f - 0.5f * wwv;
            float ab2 = 8.f + 0.5f * hh, ab3 = 8.f + 0.5f * wwv;
            float sy = 16.f * (float)y, sx = 16.f * (float)xq;
            ((float4*)out_anchor)[i] = make_float4(sy + ab0, sx + ab1, sy + ab2, sx + ab3);
        }
    } else {
        // xsplit: x fp32 -> bf16x3 planes, [split][img][kc][h][half][w][ci8]
        int pk = bid - 400;                 // 0..127
        int img = pk >> 5, kc = pk & 31;
        us8_t* XP = (us8_t*)Xs;
        for (int h2 = 0; h2 < 32; ++h2) {
#pragma unroll
            for (int i = 0; i < 8; ++i) {
                int idx = i * 256 + tid;            // [ci 16][hrow 2][w 64]
                int ci = idx >> 7, rem = idx & 127, hrow = rem >> 6, w = rem & 63;
                int h = h2 * 2 + hrow;
                xt[ci][hrow][w] = x[(((size_t)img * 512 + kc * 16 + ci) * 64 + h) * 64 + w];
            }
            __syncthreads();
            {
                int hrow = tid >> 7, st = tid & 127, half = st >> 6, w = st & 63;
                int h = h2 * 2 + hrow;
                us8_t vh, vm, vl;
#pragma unroll
                for (int j = 0; j < 8; ++j) {
                    float v = xt[half * 8 + j][hrow][w];
                    unsigned short hb = f2bf(v); float r1 = v - bf2f(hb);
                    unsigned short mb = f2bf(r1); float r2 = r1 - bf2f(mb);
                    vh[j] = hb; vm[j] = mb; vl[j] = f2bf(r2);
                }
                size_t ob = ((((size_t)img * 32 + kc) * 64 + h) * 2 + half) * 64 + w;
                XP[ob] = vh;
                XP[XS_SPL + ob] = vm;
                XP[2 * XS_SPL + ob] = vl;
            }
            __syncthreads();
        }
    }
}

// ---------------- conv1: bf16x6 MFMA, staging via global_load_lds from pre-split Xs ----------------
// (bit-identical to R7's passing kernel)
__global__ __launch_bounds__(256, 2) void conv_mfma_k(const ushort_t* __restrict__ Xs,
                                                      const ushort_t* __restrict__ Wp,
                                                      const float* __restrict__ bias,
                                                      float* __restrict__ feat) {
    __shared__ __align__(16) unsigned short xs[12672];   // 25344 B

    const int bid = blockIdx.x;
    const int xcd = bid & 7;
    const int rest = bid >> 3;
    const int coq = xcd >> 1;
    const int g = (xcd & 1) * 64 + rest;
    const int fimg = g >> 5;
    const int hp = g & 31;
    const int h0 = hp * 2;

    const int tid = threadIdx.x;
    const int lane = tid & 63;
    const int wv = tid >> 6;
    const int r = wv & 1;
    const int coh = (wv >> 1);
    const int col31 = lane & 31;
    const int halfk = lane >> 5;

    {
        u32* p = (u32*)xs;
        for (int i = tid; i < 6336; i += 256) p[i] = 0u;
    }
    __syncthreads();

    f32x16 acc[4];
#pragma unroll
    for (int q = 0; q < 4; ++q)
#pragma unroll
        for (int i = 0; i < 16; ++i) acc[q][i] = 0.f;

    const us8_t* Pw = (const us8_t*)Wp;
    static const int sal[6] = {0, 0, 1, 0, 1, 2};
    static const int sbl[6] = {0, 1, 0, 2, 1, 0};

    for (int kc = 0; kc < 32; ++kc) {
#pragma unroll
        for (int q = 0; q < 6; ++q) {
            int i = wv * 6 + q;                 // 0..23
            int split = i >> 3;
            int rem = i & 7;
            int rr = rem >> 1;
            int half = rem & 1;
            int gh = h0 + rr - 1;
            if ((unsigned)gh < 64u) {
                const char* src = (const char*)Xs +
                    (((((size_t)split * 4 + fimg) * 32 + kc) * 64 + gh) * 2 + half) * 1024 +
                    (size_t)lane * 16;
                void* dst = (void*)&xs[(((split * 2 + half) * 4 + rr) * 66 + 1) * 8];
                gl_lds16(src, dst);
            }
        }
        __syncthreads();

#pragma unroll
        for (int t = 0; t < 9; ++t) {
            const int kh = t / 3, kw = t - kh * 3;
            pun8 Bf[3][2];
#pragma unroll
            for (int sb = 0; sb < 3; ++sb)
#pragma unroll
                for (int ps = 0; ps < 2; ++ps)
                    Bf[sb][ps].u = *(const us8_t*)&xs[(((sb * 2 + halfk) * 4 + (r + kh)) * 66 +
                                                      (ps * 32 + col31 + kw)) * 8];
            pun8 Af[3][2];
            size_t abase = (((size_t)t * 32 + kc) * 16 + coq * 4 + coh * 2) * 64 + lane;
#pragma unroll
            for (int sa = 0; sa < 3; ++sa)
#pragma unroll
                for (int cs = 0; cs < 2; ++cs)
                    Af[sa][cs].u = Pw[sa * WP_SPL + abase + (size_t)cs * 64];
#pragma unroll
            for (int pp = 0; pp < 6; ++pp) {
                const int sa = sal[pp], sb = sbl[pp];
#pragma unroll
                for (int cs = 0; cs < 2; ++cs)
#pragma unroll
                    for (int ps = 0; ps < 2; ++ps)
                        acc[cs * 2 + ps] = __builtin_amdgcn_mfma_f32_32x32x16_bf16(
                            Af[sa][cs].b, Bf[sb][ps].b, acc[cs * 2 + ps], 0, 0, 0);
            }
        }
        __syncthreads();
    }

#pragma unroll
    for (int cs = 0; cs < 2; ++cs)
#pragma unroll
        for (int ps = 0; ps < 2; ++ps)
#pragma unroll
            for (int i = 0; i < 16; ++i) {
                int m = (i & 3) + 8 * (i >> 2) + 4 * halfk;
                int co = coq * 128 + coh * 64 + cs * 32 + m;
                float v = acc[cs * 2 + ps][i] + bias[co];
                v = v > 0.f ? v : 0.f;
                feat[(((size_t)fimg * 512 + co) * 64 + (h0 + r)) * 64 + (ps * 32 + col31)] = v;
            }
}

// ---------------- conv fallback: in-kernel bf16x3 split staging, 6 tiers ----------------
__global__ __launch_bounds__(256, 2) void conv_fb_k(const float* __restrict__ x,
                                                    const ushort_t* __restrict__ Wp,
                                                    const float* __restrict__ bias,
                                                    float* __restrict__ feat,
                                                    int img_base) {
    __shared__ __align__(16) unsigned short xsb[3 * 6336];

    const int bid = blockIdx.x;
    const int xcd = bid & 7;
    const int rest = bid >> 3;
    const int rest_max = gridDim.x >> 3;
    const int coq = xcd >> 1;
    const int g = (xcd & 1) * rest_max + rest;
    const int fimg = g >> 5;
    const int hp = g & 31;
    const int n = img_base + fimg;
    const int h0 = hp * 2;

    const int tid = threadIdx.x;
    const int lane = tid & 63;
    const int wv = tid >> 6;
    const int r = wv & 1;
    const int coh = (wv >> 1);
    const int col31 = lane & 31;
    const int halfk = lane >> 5;

    f32x16 acc[4];
#pragma unroll
    for (int q = 0; q < 4; ++q)
#pragma unroll
        for (int i = 0; i < 16; ++i) acc[q][i] = 0.f;

    const us8_t* Pw = (const us8_t*)Wp;
    static const int sal[6] = {0, 0, 1, 0, 1, 2};
    static const int sbl[6] = {0, 1, 0, 2, 1, 0};

    for (int kc = 0; kc < 32; ++kc) {
        for (int e = tid; e < 528; e += 256) {
            int half = e & 1;
            int rc = e >> 1;
            int rr = rc / 66;
            int cc = rc - rr * 66;
            int gr = h0 + rr - 1;
            int gc = cc - 1;
            bool inb = ((unsigned)gr < 64u) && ((unsigned)gc < 64u);
            int ci0 = kc * 16 + half * 8;
            const float* xp = x + ((((size_t)n * 512 + ci0) * 64 + gr) * 64 + gc);
            us8_t vh, vm, vl;
#pragma unroll
            for (int j = 0; j < 8; ++j) {
                float v = inb ? xp[(size_t)j * 4096] : 0.f;
                unsigned short h = f2bf(v); float r1 = v - bf2f(h);
                unsigned short m = f2bf(r1); float r2 = r1 - bf2f(m);
                vh[j] = h; vm[j] = m; vl[j] = f2bf(r2);
            }
            int off = (rr * 66 + cc) * 24 + half * 8;
            *(us8_t*)&xsb[off] = vh;
            *(us8_t*)&xsb[6336 + off] = vm;
            *(us8_t*)&xsb[12672 + off] = vl;
        }
        __syncthreads();

#pragma unroll
        for (int t = 0; t < 9; ++t) {
            const int kh = t / 3, kw = t - kh * 3;
            pun8 Bf[3][2];
            int boff0 = ((r + kh) * 66 + (col31 + kw)) * 24 + halfk * 8;
#pragma unroll
            for (int sb = 0; sb < 3; ++sb)
#pragma unroll
                for (int ps = 0; ps < 2; ++ps)
                    Bf[sb][ps].u = *(const us8_t*)&xsb[sb * 6336 + boff0 + ps * (32 * 24)];
            pun8 Af[3][2];
            size_t abase = (((size_t)t * 32 + kc) * 16 + coq * 4 + coh * 2) * 64 + lane;
#pragma unroll
            for (int sa = 0; sa < 3; ++sa)
#pragma unroll
                for (int cs = 0; cs < 2; ++cs)
                    Af[sa][cs].u = Pw[sa * WP_SPL + abase + (size_t)cs * 64];
#pragma unroll
            for (int pp = 0; pp < 6; ++pp) {
                const int sa = sal[pp], sb = sbl[pp];
#pragma unroll
                for (int cs = 0; cs < 2; ++cs)
#pragma unroll
                    for (int ps = 0; ps < 2; ++ps)
                        acc[cs * 2 + ps] = __builtin_amdgcn_mfma_f32_32x32x16_bf16(
                            Af[sa][cs].b, Bf[sb][ps].b, acc[cs * 2 + ps], 0, 0, 0);
            }
        }
        __syncthreads();
    }

#pragma unroll
    for (int cs = 0; cs < 2; ++cs)
#pragma unroll
        for (int ps = 0; ps < 2; ++ps)
#pragma unroll
            for (int i = 0; i < 16; ++i) {
                int m = (i & 3) + 8 * (i >> 2) + 4 * halfk;
                int co = coq * 128 + coh * 64 + cs * 32 + m;
                float v = acc[cs * 2 + ps][i] + bias[co];
                v = v > 0.f ? v : 0.f;
                feat[(((size_t)fimg * 512 + co) * 64 + (h0 + r)) * 64 + (ps * 32 + col31)] = v;
            }
}

// ---------------- head: 4-wave ci-split 1x1 convs + softmax-fg + loc2bbox ----------------
__global__ __launch_bounds__(256) void head_k(const float* __restrict__ feat,
                                              const float* __restrict__ wt1,
                                              const float* __restrict__ sb,
                                              const float* __restrict__ lb,
                                              const int* __restrict__ img_h,
                                              const int* __restrict__ img_w,
                                              float* __restrict__ out_loc,
                                              float* __restrict__ out_sc,
                                              float* __restrict__ boxes,
                                              float* __restrict__ scf,
                                              int img_base) {
    __shared__ float red[3][56][64];
    const int tid = threadIdx.x;
    const int lane = tid & 63;
    const int wv = tid >> 6;
    const int row = blockIdx.x;
    const int fimg = blockIdx.y;
    const int n = img_base + fimg;

    float acc[56];
#pragma unroll
    for (int i = 0; i < 56; i++) acc[i] = 0.f;

    for (int ci = wv * 128; ci < wv * 128 + 128; ++ci) {
        float f = feat[(((size_t)fimg * 512 + ci) * 64 + row) * 64 + lane];
        const float4* wp = (const float4*)(wt1 + ci * 64);
#pragma unroll
        for (int q = 0; q < 14; q++) {
            float4 w4 = wp[q];
            acc[q * 4 + 0] = fmaf(f, w4.x, acc[q * 4 + 0]);
            acc[q * 4 + 1] = fmaf(f, w4.y, acc[q * 4 + 1]);
            acc[q * 4 + 2] = fmaf(f, w4.z, acc[q * 4 + 2]);
            acc[q * 4 + 3] = fmaf(f, w4.w, acc[q * 4 + 3]);
        }
    }

    if (wv > 0) {
#pragma unroll
        for (int i = 0; i < 56; i++) red[wv - 1][i][lane] = acc[i];
    }
    __syncthreads();
    if (wv != 0) return;

#pragma unroll
    for (int i = 0; i < 56; i++)
        acc[i] = ((acc[i] + red[0][i][lane]) + red[1][i][lane]) + red[2][i][lane];

    float ihf = (float)img_h[0];
    float iwf = (float)img_w[0];
    int p = row * 64 + lane;
    size_t base = (size_t)n * NANCH + (size_t)p * 9;
    float sy = 16.f * (float)row;
    float sx = 16.f * (float)lane;
    const float rat[3] = {0.5f, 1.f, 2.f};
    const float scl[3] = {8.f, 16.f, 32.f};

#pragma unroll
    for (int a = 0; a < 9; a++) {
        int rr = a / 3, s = a % 3;
        float hh = 16.f * scl[s] * sqrtf(rat[rr]);
        float wwv = 16.f * scl[s] * sqrtf(1.f / rat[rr]);
        float ab0 = 8.f - 0.5f * hh, ab1 = 8.f - 0.5f * wwv;
        float ab2 = 8.f + 0.5f * hh, ab3 = 8.f + 0.5f * wwv;
        float a0 = sy + ab0, a1c = sx + ab1, a2 = sy + ab2, a3 = sx + ab3;

        float s0 = acc[a * 2 + 0] + sb[a * 2 + 0];
        float s1 = acc[a * 2 + 1] + sb[a * 2 + 1];
        ((float2*)out_sc)[base + a] = make_float2(s0, s1);
        float m = fmaxf(s0, s1);
        float e0 = expf(s0 - m), e1 = expf(s1 - m);
        float fg = e1 / (e0 + e1);

        float dy = acc[18 + a * 4 + 0] + lb[a * 4 + 0];
        float dx = acc[18 + a * 4 + 1] + lb[a * 4 + 1];
        float dh = acc[18 + a * 4 + 2] + lb[a * 4 + 2];
        float dw = acc[18 + a * 4 + 3] + lb[a * 4 + 3];
        ((float4*)out_loc)[base + a] = make_float4(dy, dx, dh, dw);

        float h_ = a2 - a0, w_ = a3 - a1c;
        float cy = a0 + 0.5f * h_, cx = a1c + 0.5f * w_;
        float ncy = dy * h_ + cy, ncx = dx * w_ + cx;
        float nh = expf(dh) * h_, nw = expf(dw) * w_;
        float y1 = ncy - 0.5f * nh, x1 = ncx - 0.5f * nw;
        float y2 = ncy + 0.5f * nh, x2 = ncx + 0.5f * nw;
        y1 = fminf(fmaxf(y1, 0.f), ihf);
        x1 = fminf(fmaxf(x1, 0.f), iwf);
        y2 = fminf(fmaxf(y2, 0.f), ihf);
        x2 = fminf(fmaxf(x2, 0.f), iwf);
        float hs = y2 - y1, wsz = x2 - x1;
        bool valid = (hs >= 16.f) && (wsz >= 16.f);
        ((float4*)boxes)[base + a] = make_float4(y1, x1, y2, x2);
        scf[base + a] = valid ? fg : NEG_INF_F;
    }
}

// ---------------- rss: fused radix-select + compact + bitonic sort + gather ----------------
__global__ __launch_bounds__(1024) void rss_k(const float* __restrict__ scf,
                                              const float* __restrict__ boxes,
                                              u32* __restrict__ cnt,
                                              float4* __restrict__ sbox) {
    __shared__ u64 sk[8192];              // 64 KB; first 16 KB doubles as per-wave hist
    __shared__ u32 histT[256];
    __shared__ u32 prefixS;
    __shared__ int rankS;
    __shared__ int cntS;

    const int b = blockIdx.x;
    const int tid = threadIdx.x;
    const int wv = tid >> 6;
    const float* s = scf + (size_t)b * NANCH;
    u32* hist = (u32*)sk;                 // [16][256]

    if (tid == 0) { prefixS = 0u; rankS = NPRE; }
    __syncthreads();

    for (int p = 3; p >= 0; --p) {
        for (int i = tid; i < 4096; i += 1024) hist[i] = 0u;
        __syncthreads();
        u32 prefix = prefixS;
        u32 highmask = (p == 3) ? 0u : (0xFFFFFFFFu << ((p + 1) * 8));
        for (int i = tid; i < NANCH; i += 1024) {
            u32 u = fsort(s[i]);
            if ((u & highmask) == prefix)
                atomicAdd(&hist[wv * 256 + ((u >> (p * 8)) & 255)], 1u);
        }
        __syncthreads();
        if (tid < 256) {
            u32 t = 0;
#pragma unroll
            for (int w = 0; w < 16; ++w) t += hist[w * 256 + tid];
            histT[tid] = t;
        }
        __syncthreads();
        if (tid == 0) {
            int r = rankS;
            u32 accum = 0;
            int bsel = 0;
            for (int bb = 255; bb >= 0; --bb) {
                accum += histT[bb];
                if ((int)accum >= r) {
                    bsel = bb;
                    rankS = r - (int)(accum - histT[bb]);
                    break;
                }
            }
            prefixS = prefixS | ((u32)bsel << (p * 8));
            cntS = 0;
        }
        __syncthreads();
    }

    u32 uTv = prefixS;
    for (int i = tid; i < NANCH; i += 1024) {
        float sv = s[i];
        u32 u = fsort(sv);
        if (u >= uTv && sv > -5e29f) {
            int pos = atomicAdd(&cntS, 1);
            if (pos < 8192)
                sk[pos] = ((u64)u << 32) | (u64)(0xFFFFFFFFu - (u32)i);
        }
    }
    __syncthreads();
    int count = cntS;
    if (count > 8192) count = 8192;
    for (int i = count + tid; i < 8192; i += 1024) sk[i] = 0ull;

    for (int k = 2; k <= 8192; k <<= 1) {
        for (int j = k >> 1; j > 0; j >>= 1) {
            __syncthreads();
            for (int i = tid; i < 8192; i += 1024) {
                int p = i ^ j;
                if (p > i) {
                    bool up = (i & k) == 0;
                    u64 a = sk[i], c = sk[p];
                    bool sw = up ? (a < c) : (a > c);
                    if (sw) { sk[i] = c; sk[p] = a; }
                }
            }
        }
    }
    __syncthreads();

    int S = count < NKEEP ? count : NKEEP;
    if (tid == 0) cnt[4 + b] = (u32)S;
    const float4* Bx = (const float4*)boxes;
    for (int i = tid; i < S; i += 1024) {
        u32 idx = 0xFFFFFFFFu - (u32)(sk[i] & 0xFFFFFFFFull);
        sbox[(size_t)b * CAP + i] = Bx[(size_t)b * NANCH + idx];
    }
}

// ---------------- mask build: bit (j,k) = IoU(sorted_j, sorted_k) > 0.7 ----------------
__global__ __launch_bounds__(256) void mask_k(const float4* __restrict__ sbox,
                                              u32* __restrict__ mask) {
    __shared__ float4 rb[64];
    __shared__ float ra[64];
    const int tile = blockIdx.x;
    const int b = blockIdx.y;
    const int tid = threadIdx.x;
    const int lane = tid & 63;
    const int wv = tid >> 6;
    const int r0 = tile * 64;

    if (tid < 64) {
        float4 v = sbox[(size_t)b * CAP + (r0 + tid)];
        rb[tid] = v;
        ra[tid] = (v.z - v.x) * (v.w - v.y);
    }
    __syncthreads();

    for (int chunk = (tile >> 2); chunk < 24; ++chunk) {
        int c = chunk * 256 + tid;
        float4 cb = sbox[(size_t)b * CAP + c];
        float a2 = (cb.z - cb.x) * (cb.w - cb.y);
        u64 mine = 0ull;
#pragma unroll 4
        for (int r = 0; r < 64; ++r) {
            float4 rr = rb[r];
            float ty = fmaxf(rr.x, cb.x);
            float tx = fmaxf(rr.y, cb.y);
            float by = fminf(rr.z, cb.z);
            float bx = fminf(rr.w, cb.w);
            float ih = fmaxf(by - ty, 0.f);
            float iw = fmaxf(bx - tx, 0.f);
            float inter = ih * iw;
            float iou = inter / fmaxf(ra[r] + a2 - inter, 1e-6f);
            u64 bal = __ballot(iou > 0.7f);
            if (lane == r) mine = bal;
        }
        int row = r0 + lane;
        u64* dst = (u64*)(mask + ((size_t)b * MROWS + row) * MW);
        dst[chunk * 4 + wv] = mine;
    }
}

// ---------------- scan: serial greedy (wave 0) + L2-warmer waves ----------------
__global__ __launch_bounds__(1024) void scan_k(const u32* __restrict__ mask,
                                               const float4* __restrict__ sbox,
                                               const u32* __restrict__ cnt,
                                               u32* __restrict__ sink,
                                               float4* __restrict__ out_rois) {
    const int b = blockIdx.x;
    const int tid = threadIdx.x;
    const int wv = tid >> 6;
    const int lane = tid & 63;
    const int S = (int)cnt[4 + b];

    __shared__ int keep[NPOST];
    __shared__ int posS;
    volatile int* vpos = &posS;
    if (tid == 0) *vpos = 0;
    __syncthreads();

    const u32* mbase = mask + (size_t)b * MROWS * MW;

    if (wv == 0) {
        u32 a0, a1, a2v;
        {
            int w;
            w = lane;       a0  = (w * 32 + 32 <= S) ? 0xFFFFFFFFu : ((w * 32 < S) ? ((1u << (S - w * 32)) - 1u) : 0u);
            w = 64 + lane;  a1  = (w * 32 + 32 <= S) ? 0xFFFFFFFFu : ((w * 32 < S) ? ((1u << (S - w * 32)) - 1u) : 0u);
            w = 128 + lane; a2v = (w * 32 + 32 <= S) ? 0xFFFFFFFFu : ((w * 32 < S) ? ((1u << (S - w * 32)) - 1u) : 0u);
        }

        int it = 0;
        while (it < NPOST) {
            int j;
            u64 b0 = __ballot(a0 != 0u);
            if (b0) {
                int L = __builtin_ctzll(b0);
                int cv = (lane << 5) + ctz32(a0);
                j = __shfl(cv, L);
            } else {
                u64 b1 = __ballot(a1 != 0u);
                if (b1) {
                    int L = __builtin_ctzll(b1);
                    int cv = ((64 + lane) << 5) + ctz32(a1);
                    j = __shfl(cv, L);
                } else {
                    u64 b2 = __ballot(a2v != 0u);
                    if (!b2) break;
                    int L = __builtin_ctzll(b2);
                    int cv = ((128 + lane) << 5) + ctz32(a2v);
                    j = __shfl(cv, L);
                }
            }
            if (lane == 0) { keep[it] = j; *vpos = j; }
            ++it;

            int wj = j >> 5;
            u32 bit = 1u << (j & 31);
            if (wj == lane) a0 &= ~bit;
            else if (wj == 64 + lane) a1 &= ~bit;
            else if (wj == 128 + lane) a2v &= ~bit;

            const u32* row = mbase + (size_t)j * MW;
            u32 m0 = row[lane];
            u32 m1 = row[64 + lane];
            u32 m2 = row[128 + lane];
            a0 &= ~m0; a1 &= ~m1; a2v &= ~m2;
        }

        if (lane == 0) *vpos = (1 << 28);

        int total = it;
        for (int i = lane; i < NPOST; i += 64) {
            float4 v = make_float4(0.f, 0.f, 0.f, 0.f);
            if (i < total) v = sbox[(size_t)b * CAP + keep[i]];
            out_rois[(size_t)b * NPOST + i] = v;
        }
    } else {
        u32 dummy = 0u;
        const int W = 2048;
        for (int r = wv - 1; r < MROWS; r += 15) {
            int sp = 0;
            while (*vpos + W <= r && sp < 65536) { __builtin_amdgcn_s_sleep(2); ++sp; }
            if (*vpos >= (1 << 27)) break;
            const u32* row = mbase + (size_t)r * MW;
            dummy += row[lane] + row[64 + lane] + row[128 + lane];
        }
        if (dummy == 0xDEADBEEFu) sink[b] = dummy;
    }
}

// ---------------- launch ----------------
extern "C" void kernel_launch(void* const* d_in, const int* in_sizes, int n_in,
                              void* d_out, int out_size, void* d_ws, size_t ws_size,
                              hipStream_t stream) {
    const float* x  = (const float*)d_in[0];
    const float* w1 = (const float*)d_in[1];
    const float* b1 = (const float*)d_in[2];
    const float* sw = (const float*)d_in[3];
    const float* sb = (const float*)d_in[4];
    const float* lw = (const float*)d_in[5];
    const float* lb = (const float*)d_in[6];
    const int* ih   = (const int*)d_in[7];
    const int* iw   = (const int*)d_in[8];
    float* out = (float*)d_out;

    char* ws = (char*)d_ws;
    // XL:  Wp[0,14155776) Xs[14155776,64487424) feat[64487424,98041856) RB=98041856
    // BIG: Wp[0,14155776) feat[14286848,47841280) (4 img)               RB=47841280
    // SM:  Wp[0,14155776) feat[14286848,31064064) (2 img)               RB=31064064
    const size_t NEED_XL  = 101515776;
    const size_t NEED_BIG = 51315200;
    const int mode = (ws_size >= NEED_XL) ? 2 : (ws_size >= NEED_BIG ? 1 : 0);

    ushort_t* Wp  = (ushort_t*)(ws);
    ushort_t* Xs  = (ushort_t*)(ws + 14155776);
    float* feat   = (float*)(ws + (mode == 2 ? 64487424 : 14286848));
    u32* mask     = (u32*)(ws);                       // overlays dead Wp/Xs after head
    const size_t RB = (mode == 2) ? 98041856 : (mode == 1 ? 47841280 : 31064064);
    float* wt1    = (float*)(ws + RB);                // 131072
    float* boxes  = (float*)(ws + RB + 131072);       // 2359296
    float* scf    = (float*)(ws + RB + 2490368);      // 589824
    u32* cnt      = (u32*)(ws + RB + 3080192);        // 256
    u32* sink     = (u32*)(ws + RB + 3080448);        // 256
    float4* sbox  = (float4*)(ws + RB + 3080704);     // 393216 -> end RB+3473920

    float* out_loc = out;
    float* out_sc  = out + 589824;
    float4* out_roi = (float4*)(out + 884736);
    float* out_anc = out + 889536;

    hipLaunchKernelGGL(setup_k, dim3(mode == 2 ? 528 : 400), dim3(256), 0, stream,
                       w1, sw, lw, x, Wp, Xs, wt1, out_anc);

    if (mode == 2) {
        hipLaunchKernelGGL(conv_mfma_k, dim3(512), dim3(256), 0, stream, (const ushort_t*)Xs, Wp, b1, feat);
        hipLaunchKernelGGL(head_k, dim3(64, 4), dim3(256), 0, stream, feat, wt1, sb, lb, ih, iw,
                           out_loc, out_sc, boxes, scf, 0);
    } else if (mode == 1) {
        hipLaunchKernelGGL(conv_fb_k, dim3(512), dim3(256), 0, stream, x, Wp, b1, feat, 0);
        hipLaunchKernelGGL(head_k, dim3(64, 4), dim3(256), 0, stream, feat, wt1, sb, lb, ih, iw,
                           out_loc, out_sc, boxes, scf, 0);
    } else {
        for (int pass = 0; pass < 2; ++pass) {
            hipLaunchKernelGGL(conv_fb_k, dim3(256), dim3(256), 0, stream, x, Wp, b1, feat, pass * 2);
            hipLaunchKernelGGL(head_k, dim3(64, 2), dim3(256), 0, stream, feat, wt1, sb, lb, ih, iw,
                               out_loc, out_sc, boxes, scf, pass * 2);
        }
    }

    hipLaunchKernelGGL(rss_k, dim3(4), dim3(1024), 0, stream, scf, boxes, cnt, sbox);
    hipLaunchKernelGGL(mask_k, dim3(94, 4), dim3(256), 0, stream, sbox, mask);
    hipLaunchKernelGGL(scan_k, dim3(4), dim3(1024), 0, stream, mask, sbox, cnt, sink, out_roi);
}